// Round 1
// baseline (240.299 us; speedup 1.0000x reference)
//
#include <hip/hip_runtime.h>
#include <cstdint>
#include <cstddef>

// TaskAlignedAssigner (YOLO) — B=32, A=8400, M=32, NC=80, TOPK=13
constexpr int BB = 32;
constexpr int AA = 8400;
constexpr int MM = 32;
constexpr int CC = 80;
constexpr int KK = 13;
constexpr double DEPS = 1e-9;   // module EPS
constexpr double CEPS = 1e-7;   // _ciou internal eps
constexpr double PI4 = 0.40528473456935108577;  // 4/pi^2

// ---------------------------------------------------------------------------
// Kernel A: one block per (b,m). Compute align/iou for all anchors in f64
// (tracks numpy-f64 reference ordering), write f32 planes to ws, then select
// top-13 (ties -> lowest index, lax.top_k semantics) and OR bit m into the
// per-anchor mask word when mask_in_gt && gt_mask.
// ---------------------------------------------------------------------------
__global__ __launch_bounds__(256)
void ka_align(const float* __restrict__ pd_scores,
              const float* __restrict__ pd_bboxes,
              const float* __restrict__ anc,
              const int*   __restrict__ gt_labels,
              const float* __restrict__ gt_bboxes,
              const float* __restrict__ gt_mask,
              float* __restrict__ ws_align,
              float* __restrict__ ws_iou,
              unsigned int* __restrict__ bits)
{
    __shared__ double s_align[AA];   // 67.2 KB (gfx950 WG LDS up to 160 KB)
    __shared__ double s_wv[4];
    __shared__ int    s_wi[4];

    const int bm = blockIdx.x;
    const int b = bm / MM, m = bm % MM;
    const int tid = threadIdx.x;

    const float4 gb = reinterpret_cast<const float4*>(gt_bboxes)[b*MM + m];
    const double gx1 = gb.x, gy1 = gb.y, gx2 = gb.z, gy2 = gb.w;
    const int    lab = gt_labels[b*MM + m];
    const float  gm  = gt_mask[b*MM + m];
    const bool   valid = gm > 0.0f;

    const double w1 = gx2 - gx1, h1 = gy2 - gy1 + CEPS;
    const double at1 = atan(w1 / h1);
    const size_t rowoff = (size_t)bm * AA;

    for (int a = tid; a < AA; a += 256) {
        const float2 ap = reinterpret_cast<const float2*>(anc)[a];
        const double ax = ap.x, ay = ap.y;
        const double mind = fmin(fmin(ax - gx1, ay - gy1),
                                 fmin(gx2 - ax, gy2 - ay));
        const bool fine = (mind > DEPS) && valid;

        const float4 pb = reinterpret_cast<const float4*>(pd_bboxes)[(size_t)b*AA + a];
        const double px1 = pb.x, py1 = pb.y, px2 = pb.z, py2 = pb.w;
        const double w2 = px2 - px1, h2 = py2 - py1 + CEPS;

        const double iw = fmin(gx2, px2) - fmax(gx1, px1);
        const double ih = fmin(gy2, py2) - fmax(gy1, py1);
        const double inter = fmax(iw, 0.0) * fmax(ih, 0.0);
        const double uni = w1*h1 + w2*h2 - inter + CEPS;
        const double iou = inter / uni;
        const double cw = fmax(gx2, px2) - fmin(gx1, px1);
        const double ch = fmax(gy2, py2) - fmin(gy1, py1);
        const double c2 = cw*cw + ch*ch + CEPS;
        const double ddx = px1 + px2 - gx1 - gx2;
        const double ddy = py1 + py2 - gy1 - gy2;
        const double rho2 = (ddx*ddx + ddy*ddy) * 0.25;
        const double dat = atan(w2 / h2) - at1;
        const double v = PI4 * (dat * dat);
        const double alpha = v / (v - iou + (1.0 + CEPS));
        const double ciou = iou - (rho2 / c2 + v * alpha);

        const double iouc = fine ? fmax(ciou, 0.0) : 0.0;
        const double cls  = fine ? (double)pd_scores[((size_t)b*AA + a)*CC + lab] : 0.0;
        const double i2 = iouc * iouc;
        const double algn = cls * (i2 * i2 * i2);   // alpha=1, beta=6

        ws_align[rowoff + a] = (float)algn;
        ws_iou[rowoff + a]   = (float)iouc;
        s_align[a] = algn;
    }
    __syncthreads();
    if (!valid) return;   // uniform per block

    for (int k = 0; k < KK; ++k) {
        double bv = -1.0; int ba = 0x7fffffff;
        for (int a = tid; a < AA; a += 256) {
            const double v = s_align[a];
            if (v >= 0.0 && (v > bv || (v == bv && a < ba))) { bv = v; ba = a; }
        }
        // wave64 reduce (max value, min index on ties)
        for (int off = 32; off > 0; off >>= 1) {
            const double ov = __shfl_down(bv, off);
            const int    oa = __shfl_down(ba, off);
            if (ov > bv || (ov == bv && oa < ba)) { bv = ov; ba = oa; }
        }
        const int wid = tid >> 6;
        if ((tid & 63) == 0) { s_wv[wid] = bv; s_wi[wid] = ba; }
        __syncthreads();
        if (tid == 0) {
            for (int w = 1; w < 4; ++w)
                if (s_wv[w] > bv || (s_wv[w] == bv && s_wi[w] < ba)) { bv = s_wv[w]; ba = s_wi[w]; }
            s_align[ba] = -1.0;   // remove from future rounds
            const double ax = anc[ba*2 + 0], ay = anc[ba*2 + 1];
            const double mind = fmin(fmin(ax - gx1, ay - gy1),
                                     fmin(gx2 - ax, gy2 - ay));
            if (mind > DEPS) atomicOr(&bits[b*AA + ba], 1u << m);
        }
        __syncthreads();
    }
}

// ---------------------------------------------------------------------------
// Kernel B: per (b,a) — resolve multi-assignment via argmax_m iou (first-tie),
// write final bits + labels/bboxes/tgt_idx/fg_mask (all stored as f32).
// ---------------------------------------------------------------------------
__global__ __launch_bounds__(256)
void kb_resolve(const int*   __restrict__ gt_labels,
                const float* __restrict__ gt_bboxes,
                const float* __restrict__ ws_iou,
                unsigned int* __restrict__ bits,
                float* __restrict__ out_labels,
                float* __restrict__ out_bboxes,
                float* __restrict__ out_tgt,
                float* __restrict__ out_fg)
{
    const int idx = blockIdx.x * 256 + threadIdx.x;
    if (idx >= BB * AA) return;
    const int b = idx / AA, a = idx - b * AA;

    unsigned int bt = bits[idx];
    const int cnt = __popc(bt);
    int tgt; float fg;
    if (cnt > 1) {
        const float* ip = ws_iou + (size_t)b*MM*AA + a;
        float bestv = ip[0]; int bmx = 0;
        for (int m = 1; m < MM; ++m) {
            const float v = ip[(size_t)m * AA];
            if (v > bestv) { bestv = v; bmx = m; }   // ties -> first m
        }
        tgt = bmx; bt = 1u << bmx; fg = 1.0f;
    } else if (cnt == 1) {
        tgt = __ffs(bt) - 1; fg = 1.0f;
    } else {
        tgt = 0; bt = 0u; fg = 0.0f;
    }
    bits[idx] = bt;

    int lab = gt_labels[b*MM + tgt];
    if (lab < 0) lab = 0;
    out_labels[idx] = (float)lab;
    reinterpret_cast<float4*>(out_bboxes)[idx] =
        reinterpret_cast<const float4*>(gt_bboxes)[b*MM + tgt];
    out_tgt[idx] = (float)tgt;
    out_fg[idx]  = fg;
}

// ---------------------------------------------------------------------------
// Kernel C: per (b,m) — pos_align = max_a align*mask, pos_ov = max_a iou*mask.
// ---------------------------------------------------------------------------
__global__ __launch_bounds__(256)
void kc_posmax(const float* __restrict__ ws_align,
               const float* __restrict__ ws_iou,
               const unsigned int* __restrict__ bits,
               float* __restrict__ ws_posal,
               float* __restrict__ ws_posov)
{
    __shared__ float sa[256], so[256];
    const int bm = blockIdx.x;
    const int b = bm / MM, m = bm % MM;
    const unsigned int mb = 1u << m;
    const size_t ro = (size_t)bm * AA;
    float ma = 0.0f, mo = 0.0f;
    for (int a = threadIdx.x; a < AA; a += 256) {
        if (bits[b*AA + a] & mb) {
            ma = fmaxf(ma, ws_align[ro + a]);
            mo = fmaxf(mo, ws_iou[ro + a]);
        }
    }
    sa[threadIdx.x] = ma; so[threadIdx.x] = mo;
    __syncthreads();
    for (int s = 128; s > 0; s >>= 1) {
        if (threadIdx.x < s) {
            sa[threadIdx.x] = fmaxf(sa[threadIdx.x], sa[threadIdx.x + s]);
            so[threadIdx.x] = fmaxf(so[threadIdx.x], so[threadIdx.x + s]);
        }
        __syncthreads();
    }
    if (threadIdx.x == 0) { ws_posal[bm] = sa[0]; ws_posov[bm] = so[0]; }
}

// ---------------------------------------------------------------------------
// Kernel D1: per (b,a) — norm (final mask has <=1 bit set).
// ---------------------------------------------------------------------------
__global__ __launch_bounds__(256)
void kd1_norm(const unsigned int* __restrict__ bits,
              const float* __restrict__ ws_align,
              const float* __restrict__ ws_posal,
              const float* __restrict__ ws_posov,
              float* __restrict__ ws_norm)
{
    const int idx = blockIdx.x * 256 + threadIdx.x;
    if (idx >= BB * AA) return;
    const int b = idx / AA, a = idx - b * AA;
    const unsigned int bt = bits[idx];
    double nv = 0.0;
    if (bt) {
        const int m = __ffs(bt) - 1;
        nv = (double)ws_align[((size_t)b*MM + m)*AA + a]
           * (double)ws_posov[b*MM + m]
           / ((double)ws_posal[b*MM + m] + DEPS);
    }
    ws_norm[idx] = (float)nv;
}

// ---------------------------------------------------------------------------
// Kernel D2: per element of target_scores (B*A*NC) — one-hot * norm.
// ---------------------------------------------------------------------------
__global__ __launch_bounds__(256)
void kd2_scores(const float* __restrict__ out_labels,
                const float* __restrict__ out_fg,
                const float* __restrict__ ws_norm,
                float* __restrict__ out_scores)
{
    const int i = blockIdx.x * 256 + threadIdx.x;
    if (i >= BB * AA * CC) return;
    const int cell = i / CC, c = i - cell * CC;
    float sc = 0.0f;
    if (out_fg[cell] > 0.0f && c == (int)out_labels[cell]) sc = ws_norm[cell];
    out_scores[i] = sc;
}

// ---------------------------------------------------------------------------
extern "C" void kernel_launch(void* const* d_in, const int* in_sizes, int n_in,
                              void* d_out, int out_size, void* d_ws, size_t ws_size,
                              hipStream_t stream)
{
    const float* pd_scores = (const float*)d_in[0];
    const float* pd_bboxes = (const float*)d_in[1];
    const float* anc       = (const float*)d_in[2];
    const int*   gt_labels = (const int*)d_in[3];
    const float* gt_bboxes = (const float*)d_in[4];
    const float* gt_mask   = (const float*)d_in[5];

    char* ws = (char*)d_ws;
    float* ws_align = (float*)ws;            ws += (size_t)BB*MM*AA*4;   // 34.4 MB
    float* ws_iou   = (float*)ws;            ws += (size_t)BB*MM*AA*4;   // 34.4 MB
    unsigned int* bits = (unsigned int*)ws;  ws += (size_t)BB*AA*4;      // 1.07 MB
    float* ws_norm  = (float*)ws;            ws += (size_t)BB*AA*4;      // 1.07 MB
    float* ws_posal = (float*)ws;            ws += (size_t)BB*MM*4;
    float* ws_posov = (float*)ws;            ws += (size_t)BB*MM*4;

    float* out = (float*)d_out;
    float* out_labels = out;                       // B*A
    float* out_bboxes = out + (size_t)BB*AA;       // B*A*4
    float* out_scores = out + (size_t)BB*AA*5;     // B*A*NC
    float* out_tgt    = out + (size_t)BB*AA*(5+CC);
    float* out_fg     = out + (size_t)BB*AA*(6+CC);

    hipMemsetAsync(bits, 0, (size_t)BB*AA*4, stream);

    ka_align<<<BB*MM, 256, 0, stream>>>(pd_scores, pd_bboxes, anc, gt_labels,
                                        gt_bboxes, gt_mask, ws_align, ws_iou, bits);
    kb_resolve<<<(BB*AA + 255)/256, 256, 0, stream>>>(gt_labels, gt_bboxes, ws_iou,
                                                      bits, out_labels, out_bboxes,
                                                      out_tgt, out_fg);
    kc_posmax<<<BB*MM, 256, 0, stream>>>(ws_align, ws_iou, bits, ws_posal, ws_posov);
    kd1_norm<<<(BB*AA + 255)/256, 256, 0, stream>>>(bits, ws_align, ws_posal,
                                                    ws_posov, ws_norm);
    kd2_scores<<<(BB*AA*CC + 255)/256, 256, 0, stream>>>(out_labels, out_fg,
                                                         ws_norm, out_scores);
}

// Round 2
// 209.041 us; speedup vs baseline: 1.1495x; 1.1495x over previous
//
#include <hip/hip_runtime.h>
#include <cstdint>
#include <cstddef>

// TaskAlignedAssigner (YOLO) — B=32, A=8400, M=32, NC=80, TOPK=13
constexpr int BB = 32;
constexpr int AA = 8400;
constexpr int MM = 32;
constexpr int CC = 80;
constexpr int KK = 13;
constexpr double DEPS = 1e-9;   // module EPS
constexpr double CEPS = 1e-7;   // _ciou internal eps
constexpr double PI4 = 0.40528473456935108577;  // 4/pi^2

// Full f64 CIOU (used by KB for the rare recompute paths; internal
// consistency within the kernel is all that matters).
__device__ __forceinline__ double ciou_f64(
    double gx1, double gy1, double gx2, double gy2,
    double px1, double py1, double px2, double py2)
{
    const double w1 = gx2 - gx1, h1 = gy2 - gy1 + CEPS;
    const double w2 = px2 - px1, h2 = py2 - py1 + CEPS;
    const double iw = fmin(gx2, px2) - fmax(gx1, px1);
    const double ih = fmin(gy2, py2) - fmax(gy1, py1);
    const double inter = fmax(iw, 0.0) * fmax(ih, 0.0);
    const double uni = w1*h1 + w2*h2 - inter + CEPS;
    const double iou = inter / uni;
    const double cw = fmax(gx2, px2) - fmin(gx1, px1);
    const double ch = fmax(gy2, py2) - fmin(gy1, py1);
    const double c2 = cw*cw + ch*ch + CEPS;
    const double ddx = px1 + px2 - gx1 - gx2;
    const double ddy = py1 + py2 - gy1 - gy2;
    const double rho2 = (ddx*ddx + ddy*ddy) * 0.25;
    const double dat = atan(w2 / h2) - atan(w1 / h1);
    const double v = PI4 * (dat * dat);
    const double alpha = v / (v - iou + (1.0 + CEPS));
    return iou - (rho2 / c2 + v * alpha);
}

// ---------------------------------------------------------------------------
// KA: one thread per (b,a), loop over m. atan(w2/h2) hoisted per anchor,
// gt-side constants (incl. atan(w1/h1)) in LDS. Writes f64 align plane +
// per-anchor fine bitmask.
// ---------------------------------------------------------------------------
__global__ __launch_bounds__(256)
void ka_align(const float* __restrict__ pd_scores,
              const float* __restrict__ pd_bboxes,
              const float* __restrict__ anc,
              const int*   __restrict__ gt_labels,
              const float* __restrict__ gt_bboxes,
              const float* __restrict__ gt_mask,
              double* __restrict__ alignd,
              unsigned int* __restrict__ fine_bits)
{
    __shared__ double s_gx1[MM], s_gy1[MM], s_gx2[MM], s_gy2[MM];
    __shared__ double s_w1h1[MM], s_at1[MM];
    __shared__ int s_lab[MM];
    __shared__ unsigned int s_valid;

    const int b = blockIdx.y;
    const int a = blockIdx.x * 256 + threadIdx.x;

    if (threadIdx.x == 0) s_valid = 0;
    __syncthreads();
    if (threadIdx.x < MM) {
        const int m = threadIdx.x;
        const float4 gb = reinterpret_cast<const float4*>(gt_bboxes)[b*MM + m];
        const double gx1 = gb.x, gy1 = gb.y, gx2 = gb.z, gy2 = gb.w;
        s_gx1[m] = gx1; s_gy1[m] = gy1; s_gx2[m] = gx2; s_gy2[m] = gy2;
        const double w1 = gx2 - gx1, h1 = gy2 - gy1 + CEPS;
        s_w1h1[m] = w1 * h1;
        s_at1[m]  = atan(w1 / h1);
        s_lab[m]  = gt_labels[b*MM + m];
        if (gt_mask[b*MM + m] > 0.0f) atomicOr(&s_valid, 1u << m);
    }
    __syncthreads();
    if (a >= AA) return;

    const float2 ap = reinterpret_cast<const float2*>(anc)[a];
    const double ax = ap.x, ay = ap.y;
    const float4 pb = reinterpret_cast<const float4*>(pd_bboxes)[(size_t)b*AA + a];
    const double px1 = pb.x, py1 = pb.y, px2 = pb.z, py2 = pb.w;
    const double w2 = px2 - px1, h2 = py2 - py1 + CEPS;
    const double at2 = atan(w2 / h2);
    const double w2h2 = w2 * h2;
    const float* srow = pd_scores + ((size_t)b*AA + a) * CC;
    const unsigned int vmask = s_valid;
    const size_t obase = (size_t)b * MM * AA + a;
    unsigned int fb = 0;

    #pragma unroll 4
    for (int m = 0; m < MM; ++m) {
        const double gx1 = s_gx1[m], gy1 = s_gy1[m];
        const double gx2 = s_gx2[m], gy2 = s_gy2[m];
        const double mind = fmin(fmin(ax - gx1, ay - gy1),
                                 fmin(gx2 - ax, gy2 - ay));
        const bool fine = (mind > DEPS) && ((vmask >> m) & 1u);

        const double iw = fmin(gx2, px2) - fmax(gx1, px1);
        const double ih = fmin(gy2, py2) - fmax(gy1, py1);
        const double inter = fmax(iw, 0.0) * fmax(ih, 0.0);
        const double uni = s_w1h1[m] + w2h2 - inter + CEPS;
        const double iou = inter / uni;
        const double cw = fmax(gx2, px2) - fmin(gx1, px1);
        const double ch = fmax(gy2, py2) - fmin(gy1, py1);
        const double c2 = cw*cw + ch*ch + CEPS;
        const double ddx = px1 + px2 - gx1 - gx2;
        const double ddy = py1 + py2 - gy1 - gy2;
        const double rho2 = (ddx*ddx + ddy*ddy) * 0.25;
        const double dat = at2 - s_at1[m];
        const double v = PI4 * (dat * dat);
        const double alpha = v / (v - iou + (1.0 + CEPS));
        const double ciou = iou - (rho2 / c2 + v * alpha);

        const double iouc = fine ? fmax(ciou, 0.0) : 0.0;
        const double cls  = fine ? (double)srow[s_lab[m]] : 0.0;
        const double i2 = iouc * iouc;
        alignd[obase + (size_t)m * AA] = cls * (i2 * i2 * i2);
        if (fine) fb |= 1u << m;
    }
    fine_bits[(size_t)b*AA + a] = fb;
}

// ---------------------------------------------------------------------------
// KT: per (b,m) block — load f64 align row to LDS, 13 rounds of
// (max, lowest-index-on-tie) argmax = lax.top_k semantics.
// ---------------------------------------------------------------------------
__global__ __launch_bounds__(256)
void kt_topk(const double* __restrict__ alignd,
             const unsigned int* __restrict__ fine_bits,
             const float* __restrict__ gt_mask,
             unsigned int* __restrict__ bits)
{
    __shared__ double s_align[AA];   // 67.2 KB
    __shared__ double s_wv[4];
    __shared__ int    s_wi[4];

    const int bm = blockIdx.x;
    const int b = bm / MM, m = bm % MM;
    const int tid = threadIdx.x;
    if (gt_mask[bm] <= 0.0f) return;   // uniform per block

    const size_t ro = (size_t)bm * AA;
    for (int a = tid; a < AA; a += 256) s_align[a] = alignd[ro + a];
    __syncthreads();

    for (int k = 0; k < KK; ++k) {
        double bv = -1.0; int ba = 0x7fffffff;
        for (int a = tid; a < AA; a += 256) {
            const double v = s_align[a];
            if (v >= 0.0 && (v > bv || (v == bv && a < ba))) { bv = v; ba = a; }
        }
        for (int off = 32; off > 0; off >>= 1) {
            const double ov = __shfl_down(bv, off);
            const int    oa = __shfl_down(ba, off);
            if (ov > bv || (ov == bv && oa < ba)) { bv = ov; ba = oa; }
        }
        const int wid = tid >> 6;
        if ((tid & 63) == 0) { s_wv[wid] = bv; s_wi[wid] = ba; }
        __syncthreads();
        if (tid == 0) {
            for (int w = 1; w < 4; ++w)
                if (s_wv[w] > bv || (s_wv[w] == bv && s_wi[w] < ba)) { bv = s_wv[w]; ba = s_wi[w]; }
            s_align[ba] = -1.0;
            if (fine_bits[b*AA + ba] & (1u << m))
                atomicOr(&bits[b*AA + ba], 1u << m);
        }
        __syncthreads();
    }
}

// ---------------------------------------------------------------------------
// KB: per (b,a) — resolve multi-assignment (argmax_m of f64-recomputed masked
// iou, first-tie), write labels/bboxes/tgt/fg, and fuse pos_align/pos_ov via
// float-as-uint atomicMax (all values >= 0).
// ---------------------------------------------------------------------------
__global__ __launch_bounds__(256)
void kb_resolve(const int*   __restrict__ gt_labels,
                const float* __restrict__ gt_bboxes,
                const float* __restrict__ pd_bboxes,
                const unsigned int* __restrict__ fine_bits,
                const double* __restrict__ alignd,
                unsigned int* __restrict__ bits,
                float* __restrict__ out_labels,
                float* __restrict__ out_bboxes,
                float* __restrict__ out_tgt,
                float* __restrict__ out_fg,
                unsigned int* __restrict__ posal_u,
                unsigned int* __restrict__ posov_u)
{
    const int idx = blockIdx.x * 256 + threadIdx.x;
    if (idx >= BB * AA) return;
    const int b = idx / AA, a = idx - b * AA;

    unsigned int bt = bits[idx];
    const int cnt = __popc(bt);
    int tgt = 0; float fg = 0.0f;

    if (cnt > 0) {
        fg = 1.0f;
        const float4 pb = reinterpret_cast<const float4*>(pd_bboxes)[(size_t)b*AA + a];
        const unsigned int fb = fine_bits[idx];
        double iou_t = 0.0;
        if (cnt > 1) {
            double bestv = -1.0; int bmx = 0;
            for (int m = 0; m < MM; ++m) {
                double v = 0.0;
                if ((fb >> m) & 1u) {
                    const float4 gb = reinterpret_cast<const float4*>(gt_bboxes)[b*MM + m];
                    v = fmax(ciou_f64(gb.x, gb.y, gb.z, gb.w, pb.x, pb.y, pb.z, pb.w), 0.0);
                }
                if (v > bestv) { bestv = v; bmx = m; }   // ties -> first m
            }
            tgt = bmx; bt = 1u << bmx; iou_t = bestv;
        } else {
            tgt = __ffs(bt) - 1;
            if ((fb >> tgt) & 1u) {
                const float4 gb = reinterpret_cast<const float4*>(gt_bboxes)[b*MM + tgt];
                iou_t = fmax(ciou_f64(gb.x, gb.y, gb.z, gb.w, pb.x, pb.y, pb.z, pb.w), 0.0);
            }
        }
        const float al = (float)alignd[((size_t)b*MM + tgt)*AA + a];
        atomicMax(&posal_u[b*MM + tgt], __float_as_uint(al));
        atomicMax(&posov_u[b*MM + tgt], __float_as_uint((float)iou_t));
    }
    bits[idx] = bt;

    int lab = gt_labels[b*MM + tgt];
    if (lab < 0) lab = 0;
    out_labels[idx] = (float)lab;
    reinterpret_cast<float4*>(out_bboxes)[idx] =
        reinterpret_cast<const float4*>(gt_bboxes)[b*MM + tgt];
    out_tgt[idx] = (float)tgt;
    out_fg[idx]  = fg;
}

// ---------------------------------------------------------------------------
// KD1: per (b,a) — norm (final mask has <=1 bit set).
// ---------------------------------------------------------------------------
__global__ __launch_bounds__(256)
void kd1_norm(const unsigned int* __restrict__ bits,
              const double* __restrict__ alignd,
              const unsigned int* __restrict__ posal_u,
              const unsigned int* __restrict__ posov_u,
              float* __restrict__ ws_norm)
{
    const int idx = blockIdx.x * 256 + threadIdx.x;
    if (idx >= BB * AA) return;
    const int b = idx / AA, a = idx - b * AA;
    const unsigned int bt = bits[idx];
    double nv = 0.0;
    if (bt) {
        const int m = __ffs(bt) - 1;
        nv = alignd[((size_t)b*MM + m)*AA + a]
           * (double)__uint_as_float(posov_u[b*MM + m])
           / ((double)__uint_as_float(posal_u[b*MM + m]) + DEPS);
    }
    ws_norm[idx] = (float)nv;
}

// ---------------------------------------------------------------------------
// KD2: float4 per thread over target_scores (B*A*NC).
// ---------------------------------------------------------------------------
__global__ __launch_bounds__(256)
void kd2_scores(const float* __restrict__ out_labels,
                const float* __restrict__ out_fg,
                const float* __restrict__ ws_norm,
                float* __restrict__ out_scores)
{
    const int i = blockIdx.x * 256 + threadIdx.x;
    if (i >= BB * AA * (CC/4)) return;
    const int cell = i / (CC/4);
    const int q = (i - cell * (CC/4)) * 4;
    float4 r = make_float4(0.f, 0.f, 0.f, 0.f);
    if (out_fg[cell] > 0.0f) {
        const int lab = (int)out_labels[cell];
        if (lab >= q && lab < q + 4) {
            const float n = ws_norm[cell];
            if (lab == q)     r.x = n;
            if (lab == q + 1) r.y = n;
            if (lab == q + 2) r.z = n;
            if (lab == q + 3) r.w = n;
        }
    }
    reinterpret_cast<float4*>(out_scores)[i] = r;
}

// ---------------------------------------------------------------------------
extern "C" void kernel_launch(void* const* d_in, const int* in_sizes, int n_in,
                              void* d_out, int out_size, void* d_ws, size_t ws_size,
                              hipStream_t stream)
{
    const float* pd_scores = (const float*)d_in[0];
    const float* pd_bboxes = (const float*)d_in[1];
    const float* anc       = (const float*)d_in[2];
    const int*   gt_labels = (const int*)d_in[3];
    const float* gt_bboxes = (const float*)d_in[4];
    const float* gt_mask   = (const float*)d_in[5];

    char* ws = (char*)d_ws;
    double* alignd = (double*)ws;               ws += (size_t)BB*MM*AA*8;   // 68.8 MB
    unsigned int* fine_bits = (unsigned int*)ws; ws += (size_t)BB*AA*4;     // 1.07 MB
    unsigned int* bits = (unsigned int*)ws;      ws += (size_t)BB*AA*4;     // 1.07 MB
    unsigned int* posal_u = (unsigned int*)ws;   ws += (size_t)BB*MM*4;
    unsigned int* posov_u = (unsigned int*)ws;   ws += (size_t)BB*MM*4;
    float* ws_norm = (float*)ws;                 ws += (size_t)BB*AA*4;

    float* out = (float*)d_out;
    float* out_labels = out;                       // B*A
    float* out_bboxes = out + (size_t)BB*AA;       // B*A*4
    float* out_scores = out + (size_t)BB*AA*5;     // B*A*NC
    float* out_tgt    = out + (size_t)BB*AA*(5+CC);
    float* out_fg     = out + (size_t)BB*AA*(6+CC);

    // bits + posal + posov are contiguous -> one async memset
    hipMemsetAsync(bits, 0, (size_t)BB*AA*4 + (size_t)BB*MM*8, stream);

    dim3 ga((AA + 255)/256, BB);
    ka_align<<<ga, 256, 0, stream>>>(pd_scores, pd_bboxes, anc, gt_labels,
                                     gt_bboxes, gt_mask, alignd, fine_bits);
    kt_topk<<<BB*MM, 256, 0, stream>>>(alignd, fine_bits, gt_mask, bits);
    kb_resolve<<<(BB*AA + 255)/256, 256, 0, stream>>>(gt_labels, gt_bboxes, pd_bboxes,
                                                      fine_bits, alignd, bits,
                                                      out_labels, out_bboxes,
                                                      out_tgt, out_fg,
                                                      posal_u, posov_u);
    kd1_norm<<<(BB*AA + 255)/256, 256, 0, stream>>>(bits, alignd, posal_u,
                                                    posov_u, ws_norm);
    kd2_scores<<<(BB*AA*(CC/4) + 255)/256, 256, 0, stream>>>(out_labels, out_fg,
                                                             ws_norm, out_scores);
}